// Round 8
// baseline (317.057 us; speedup 1.0000x reference)
//
#include <hip/hip_runtime.h>

typedef _Float16 half4 __attribute__((ext_vector_type(4)));
typedef _Float16 half8 __attribute__((ext_vector_type(8)));
typedef float f32x4 __attribute__((ext_vector_type(4)));

#define NNODE 8192
#define NHID  256
#define RCAP  128
#define KCAP  64
#define GLS   72    // gemm lds row stride (fp16): 144B = 9 quads, conflict-free

struct SmemGemm  { _Float16 sA[64][GLS]; _Float16 sB[64][GLS]; };
struct SmemDedup { int lc[2][RCAP]; float lw[2][RCAP]; unsigned char kp[2][RCAP];
                   int cw[2][2]; float rw[2][2]; };
// per-wave medoid scratch (wave-synchronous, no barriers): 768B/wave
struct SmemMedoidW { float sq[64]; float cst[64]; float av[64]; };

// ---------------------------------------------------------------- GEMM tile body (fp16 A, fp16 BT)
__device__ __forceinline__ void gemm_body(
    char* smraw, const _Float16* __restrict__ Ahi, const _Float16* __restrict__ BT,
    _Float16* __restrict__ Chi, int K, int bm, int bn) {
    SmemGemm& sm = *(SmemGemm*)smraw;
    const int t = threadIdx.x;
    const int lane = t & 63, L15 = lane & 15, q = lane >> 4;
    const int w = t >> 6, wr = w >> 1, wc = w & 1;
    f32x4 acc[2][2];
#pragma unroll
    for (int a = 0; a < 2; ++a)
#pragma unroll
        for (int b2 = 0; b2 < 2; ++b2) acc[a][b2] = (f32x4){0.f, 0.f, 0.f, 0.f};

    for (int k0 = 0; k0 < K; k0 += 64) {
#pragma unroll
        for (int i = 0; i < 2; ++i) {
            int row = i * 32 + (t >> 3), ch = t & 7;
            *(half8*)&sm.sA[row][ch * 8] =
                *(const half8*)(Ahi + (size_t)(bm + row) * K + k0 + ch * 8);
            *(half8*)&sm.sB[row][ch * 8] =
                *(const half8*)(BT + (size_t)(bn + row) * K + k0 + ch * 8);
        }
        __syncthreads();
#pragma unroll
        for (int ks = 0; ks < 2; ++ks) {
            const int ko = ks * 32 + q * 8;
            half8 ah[2], bh[2];
#pragma unroll
            for (int tr = 0; tr < 2; ++tr)
                ah[tr] = *(const half8*)&sm.sA[32 * wr + 16 * tr + L15][ko];
#pragma unroll
            for (int tc = 0; tc < 2; ++tc)
                bh[tc] = *(const half8*)&sm.sB[32 * wc + 16 * tc + L15][ko];
#pragma unroll
            for (int tr = 0; tr < 2; ++tr)
#pragma unroll
                for (int tc = 0; tc < 2; ++tc)
                    acc[tr][tc] = __builtin_amdgcn_mfma_f32_16x16x32_f16(ah[tr], bh[tc], acc[tr][tc], 0, 0, 0);
        }
        __syncthreads();
    }
#pragma unroll
    for (int tr = 0; tr < 2; ++tr)
#pragma unroll
        for (int tc = 0; tc < 2; ++tc)
#pragma unroll
            for (int r = 0; r < 4; ++r) {
                int rowg = bm + 32 * wr + 16 * tr + q * 4 + r;
                int colg = bn + 32 * wc + 16 * tc + L15;
                Chi[(size_t)rowg * NHID + colg] = (_Float16)acc[tr][tc][r];
            }
}

// ---------------------------------------------------------------- dedup body (2 rows per call)
__device__ __forceinline__ void dedup_body(
    char* smraw, const int* __restrict__ nbr, const int* __restrict__ rowcnt,
    const int* __restrict__ deg, int* __restrict__ cols, float* __restrict__ wout,
    float* __restrict__ rsum, int grp) {
    SmemDedup& sm = *(SmemDedup*)smraw;
    const int t = threadIdx.x;
    const int half = t >> 7, st = t & 127;
    const int wid = st >> 6, lane = t & 63;
    const int r = grp * 2 + half;
    int n = rowcnt[r]; if (n > RCAP) n = RCAP;
    if (st < n) sm.lc[half][st] = nbr[r * RCAP + st];
    __syncthreads();
    float dr = 1.f / sqrtf((float)deg[r]);
    bool keep = false; float wv = 0.f;
    if (st < n) {
        int c = sm.lc[half][st];
        int mult = 0; bool first = true;
        for (int i = 0; i < n; ++i) {
            int ci = sm.lc[half][i];
            if (ci == c) { mult++; if (i < st) first = false; }
        }
        keep = first;
        if (first) wv = (float)mult * dr * (1.f / sqrtf((float)deg[c]));
    }
    sm.kp[half][st] = keep ? 1 : 0; sm.lw[half][st] = wv;
    float rv = wv;
#pragma unroll
    for (int d = 1; d < 64; d <<= 1) rv += __shfl_xor(rv, d, 64);
    unsigned long long b = __ballot(keep);
    int pre = __popcll(b & ((1ull << lane) - 1ull));
    int cw = __popcll(b);
    if (lane == 0) { sm.cw[half][wid] = cw; sm.rw[half][wid] = rv; }
    __syncthreads();
    int total = sm.cw[half][0] + sm.cw[half][1];
    if (st == 0) rsum[r] = sm.rw[half][0] + sm.rw[half][1];
    const int base = r * KCAP;
    if (total <= KCAP) {
        int off = (wid ? sm.cw[half][0] : 0) + pre;
        if (keep) { cols[base + off] = sm.lc[half][st]; wout[base + off] = wv; }
        for (int m = total + st; m < KCAP; m += 128) { cols[base + m] = r; wout[base + m] = 0.f; }
    } else if (st == 0) {
        for (int s = 0; s < KCAP; ++s) {
            int best = -1;
            for (int i = 0; i < n; ++i) {
                if (!sm.kp[half][i]) continue;
                if (best < 0 || sm.lw[half][i] > sm.lw[half][best] ||
                    (sm.lw[half][i] == sm.lw[half][best] && sm.lc[half][i] < sm.lc[half][best])) best = i;
            }
            cols[base + s] = sm.lc[half][best]; wout[base + s] = sm.lw[half][best]; sm.kp[half][best] = 0;
        }
    }
}

// ---------------------------------------------------------------- medoid cost-tile macros
// off-diag tile (r<c): forward (a_row*dist -> cst[col]) + transpose (a_col*dist -> cst[row])
#define TILE_OFF(r, c, A) { \
    const float sqc = sm.sq[16*(c) + L15]; \
    const float acl = sm.av[16*(c) + L15]; \
    float pj = 0.f; float pt[4]; \
    _Pragma("unroll") \
    for (int i = 0; i < 4; ++i) { \
        float d2 = sm.sq[16*(r) + q*4 + i] + sqc - 2.f * (A)[i]; \
        float dist = d2 > 0.f ? __builtin_amdgcn_sqrtf(d2) : 0.f; \
        pj = fmaf(sm.av[16*(r) + q*4 + i], dist, pj); \
        pt[i] = acl * dist; \
    } \
    pj += __shfl_xor(pj, 16, 64); pj += __shfl_xor(pj, 32, 64); \
    if (q == 0) sm.cst[16*(c) + L15] += pj; \
    _Pragma("unroll") \
    for (int i = 0; i < 4; ++i) { \
        pt[i] += __shfl_xor(pt[i], 1, 64); \
        pt[i] += __shfl_xor(pt[i], 2, 64); \
        pt[i] += __shfl_xor(pt[i], 4, 64); \
        pt[i] += __shfl_xor(pt[i], 8, 64); \
    } \
    if (L15 == 0) { \
        sm.cst[16*(r) + q*4 + 0] += pt[0]; \
        sm.cst[16*(r) + q*4 + 1] += pt[1]; \
        sm.cst[16*(r) + q*4 + 2] += pt[2]; \
        sm.cst[16*(r) + q*4 + 3] += pt[3]; \
    } }

#define TILE_DIAG(g, A) { \
    const float sqc = sm.sq[16*(g) + L15]; \
    float pj = 0.f; \
    _Pragma("unroll") \
    for (int i = 0; i < 4; ++i) { \
        float d2 = sm.sq[16*(g) + q*4 + i] + sqc - 2.f * (A)[i]; \
        float dist = d2 > 0.f ? __builtin_amdgcn_sqrtf(d2) : 0.f; \
        pj = fmaf(sm.av[16*(g) + q*4 + i], dist, pj); \
    } \
    pj += __shfl_xor(pj, 16, 64); pj += __shfl_xor(pj, 32, 64); \
    if (q == 0) sm.cst[16*(g) + L15] += pj; }

#define MFMA16(a, b, c) __builtin_amdgcn_mfma_f32_16x16x32_f16((a), (b), (c), 0, 0, 0)

// ================================================================ D3/D5: medoid — ONE WAVE PER NODE, zero barriers
// Gram C = S.S^T via 10 upper-triangle 16x16x32 MFMA tiles; fragments loaded
// directly from global (row-fragment layout == global layout), each node row
// fetched exactly once per wave (= once per node). Cost/softmax wave-local
// via per-wave LDS scratch; mirror contributions via dist symmetry.
__global__ __launch_bounds__(256, 5) void k_medoid(
    const _Float16* __restrict__ X, const float* __restrict__ bias,
    float* __restrict__ OutF, _Float16* __restrict__ OutHi,
    const int* __restrict__ cols, const float* __restrict__ wts,
    const float* __restrict__ rsum, int writeH) {
    __shared__ SmemMedoidW smw[4];
    const int t = threadIdx.x;
    const int w = t >> 6, lane = t & 63;
    const int node = (int)blockIdx.x * 4 + w;
    SmemMedoidW& sm = smw[w];
    const int L15 = lane & 15, q = lane >> 4;

    const int   base    = node * KCAP;
    const int   cid_own = cols[base + lane];
    const float a_own   = wts[base + lane];
    const float rs      = rsum[node];

    sm.av[lane]  = a_own;
    sm.cst[lane] = 0.f;

    // fragment base pointers: row-group g covers rows 16g+L15
    const _Float16* rb[4];
#pragma unroll
    for (int g = 0; g < 4; ++g) {
        int cg = __shfl(cid_own, g * 16 + L15, 64);
        rb[g] = X + ((size_t)cg << 8) + q * 8;
    }

    f32x4 a00 = (f32x4){0.f,0.f,0.f,0.f}, a01 = a00, a02 = a00, a03 = a00;
    f32x4 a11 = a00, a12 = a00, a13 = a00, a22 = a00, a23 = a00, a33 = a00;

#pragma unroll
    for (int kc = 0; kc < 8; ++kc) {
        half8 f0 = *(const half8*)(rb[0] + kc * 32);
        half8 f1 = *(const half8*)(rb[1] + kc * 32);
        half8 f2 = *(const half8*)(rb[2] + kc * 32);
        half8 f3 = *(const half8*)(rb[3] + kc * 32);
        a00 = MFMA16(f0, f0, a00); a01 = MFMA16(f0, f1, a01);
        a02 = MFMA16(f0, f2, a02); a03 = MFMA16(f0, f3, a03);
        a11 = MFMA16(f1, f1, a11); a12 = MFMA16(f1, f2, a12);
        a13 = MFMA16(f1, f3, a13); a22 = MFMA16(f2, f2, a22);
        a23 = MFMA16(f2, f3, a23); a33 = MFMA16(f3, f3, a33);
    }

    // diag extraction: C layout col=L15, row=q*4+i -> diag where L15==q*4+i
#pragma unroll
    for (int i = 0; i < 4; ++i)
        if (L15 == q * 4 + i) {
            sm.sq[ 0 + L15] = a00[i];
            sm.sq[16 + L15] = a11[i];
            sm.sq[32 + L15] = a22[i];
            sm.sq[48 + L15] = a33[i];
        }
    __builtin_amdgcn_wave_barrier();   // order diag writes before cost reads

    TILE_DIAG(0, a00) TILE_DIAG(1, a11) TILE_DIAG(2, a22) TILE_DIAG(3, a33)
    TILE_OFF(0, 1, a01) TILE_OFF(0, 2, a02) TILE_OFF(0, 3, a03)
    TILE_OFF(1, 2, a12) TILE_OFF(1, 3, a13) TILE_OFF(2, 3, a23)

    __builtin_amdgcn_wave_barrier();   // order cst RMWs before softmax read
    // ---- softmax (wave-wide, weight-corrected, rsum-scaled)
    const float cj = sm.cst[lane];
    const bool valid = a_own > 0.f;
    float mn = valid ? cj : 3.4e38f;
#pragma unroll
    for (int d = 1; d < 64; d <<= 1) mn = fminf(mn, __shfl_xor(mn, d, 64));
    float e = valid ? __expf(mn - cj) * a_own : 0.f;
    float s = e;
#pragma unroll
    for (int d = 1; d < 64; d <<= 1) s += __shfl_xor(s, d, 64);
    const float u_own = e * (rs / s);

    // ---- weighted-sum epilogue: 32 lanes x 8 dims, 2 j's per iteration
    const int d8 = (lane & 31) * 8, jo = lane >> 5;
    float o[8] = {0.f,0.f,0.f,0.f,0.f,0.f,0.f,0.f};
#pragma unroll
    for (int it = 0; it < 32; ++it) {
        int j = it * 2 + jo;
        float u  = __shfl(u_own, j, 64);
        int  cj2 = __shfl(cid_own, j, 64);
        half8 xv = *(const half8*)(X + ((size_t)cj2 << 8) + d8);
#pragma unroll
        for (int e2 = 0; e2 < 8; ++e2) o[e2] = fmaf(u, (float)xv[e2], o[e2]);
    }
#pragma unroll
    for (int e2 = 0; e2 < 8; ++e2) o[e2] += __shfl_xor(o[e2], 32, 64);
    if (lane < 32) {
        float4 ba = *(const float4*)&bias[d8];
        float4 bb = *(const float4*)&bias[d8 + 4];
        float r0 = fmaxf(o[0] + ba.x, 0.f), r1 = fmaxf(o[1] + ba.y, 0.f);
        float r2 = fmaxf(o[2] + ba.z, 0.f), r3 = fmaxf(o[3] + ba.w, 0.f);
        float r4 = fmaxf(o[4] + bb.x, 0.f), r5 = fmaxf(o[5] + bb.y, 0.f);
        float r6 = fmaxf(o[6] + bb.z, 0.f), r7 = fmaxf(o[7] + bb.w, 0.f);
        size_t ob = (size_t)node * NHID + d8;
        if (writeH) {
            half8 hv;
            hv[0] = (_Float16)r0; hv[1] = (_Float16)r1; hv[2] = (_Float16)r2; hv[3] = (_Float16)r3;
            hv[4] = (_Float16)r4; hv[5] = (_Float16)r5; hv[6] = (_Float16)r6; hv[7] = (_Float16)r7;
            *(half8*)&OutHi[ob] = hv;
        } else {
            *(float4*)&OutF[ob]     = make_float4(r0, r1, r2, r3);
            *(float4*)&OutF[ob + 4] = make_float4(r4, r5, r6, r7);
        }
    }
}

// ================================================================ D1: prep (xh, w1T, w2T) ∥ edge scatter
#define PREPB 512
__global__ __launch_bounds__(256) void k_prep_scatter(
    const float* __restrict__ x, _Float16* __restrict__ xh,
    const float* __restrict__ W1, _Float16* __restrict__ w1T,
    const float* __restrict__ W2, _Float16* __restrict__ w2T,
    const void* edges, int* rowcnt, int* nbr, int* deg, int E) {
    const int t = threadIdx.x;
    if ((int)blockIdx.x < PREPB) {
        const int gid = blockIdx.x * 256 + t, nthr = PREPB * 256;
        for (int i = gid; i < NNODE * 512 / 4; i += nthr) {
            float4 v = ((const float4*)x)[i];
            half4 h;
            h[0] = (_Float16)v.x; h[1] = (_Float16)v.y;
            h[2] = (_Float16)v.z; h[3] = (_Float16)v.w;
            *(half4*)&xh[4 * (size_t)i] = h;
        }
        for (int i = gid; i < 512 * NHID; i += nthr) {
            int k = i >> 8, n = i & 255;
            w1T[(size_t)n * 512 + k] = (_Float16)W1[i];
        }
        for (int i = gid; i < NHID * NHID; i += nthr) {
            int k = i >> 8, n = i & 255;
            w2T[(size_t)n * 256 + k] = (_Float16)W2[i];
        }
    } else {
        __shared__ int sflag;
        if (t < 64) {   // per-block dtype probe (L2-hot)
            const long long* e = (const long long*)edges;
            long long v = e[t];
            unsigned long long bad = __ballot(v < 0 || v >= (long long)NNODE);
            if (t == 0) sflag = (bad == 0) ? 1 : 0;
        }
        __syncthreads();
        const int fl = sflag;
        int i = ((int)blockIdx.x - PREPB) * 256 + t;
        if (i >= E + NNODE) return;
        int r, c;
        if (i < E) {
            if (fl) {
                const long long* e = (const long long*)edges;
                r = (int)e[i]; c = (int)e[E + i];
            } else {
                const int* e = (const int*)edges;
                r = e[i]; c = e[E + i];
            }
        } else { r = i - E; c = r; }   // self loop
        int pos = atomicAdd(&rowcnt[r], 1);
        if (pos < RCAP) nbr[r * RCAP + pos] = c;
        atomicAdd(&deg[c], 1);
    }
}

// ================================================================ D2: gemm1 (blocks 0..511) ∥ dedup
__global__ __launch_bounds__(256) void k_gemm1_dedup(
    const _Float16* __restrict__ xh, const _Float16* __restrict__ w1T,
    _Float16* __restrict__ X1,
    const int* __restrict__ nbr, const int* __restrict__ rowcnt,
    const int* __restrict__ deg,
    int* __restrict__ cols, float* __restrict__ wA, float* __restrict__ rsum) {
    __shared__ __align__(16) char smem[sizeof(SmemGemm)];
    if ((int)blockIdx.x < 512) {
        int g = blockIdx.x;
        gemm_body(smem, xh, w1T, X1, 512, (g >> 2) * 64, (g & 3) * 64);
    } else {
        dedup_body(smem, nbr, rowcnt, deg, cols, wA, rsum, (int)blockIdx.x - 512);
    }
}

// ================================================================ D4: gemm layer 2
__global__ __launch_bounds__(256) void k_gemm2(
    const _Float16* __restrict__ Hh, const _Float16* __restrict__ w2T,
    _Float16* __restrict__ X2) {
    __shared__ __align__(16) char smem[sizeof(SmemGemm)];
    gemm_body(smem, Hh, w2T, X2, 256, blockIdx.x * 64, blockIdx.y * 64);
}

// ================================================================ launch
extern "C" void kernel_launch(void* const* d_in, const int* in_sizes, int n_in,
                              void* d_out, int out_size, void* d_ws, size_t ws_size,
                              hipStream_t stream) {
    const float* x  = (const float*)d_in[0];
    const void*  ei = d_in[1];
    const float* W1 = (const float*)d_in[2];
    const float* b1 = (const float*)d_in[3];
    const float* W2 = (const float*)d_in[4];
    const float* b2 = (const float*)d_in[5];
    float* out = (float*)d_out;
    const int E = in_sizes[1] / 2;

    char* p = (char*)d_ws;
    auto alloc = [&](size_t bytes) { char* q = p; p += (bytes + 255) & ~(size_t)255; return q; };
    int*      cnt    = (int*)alloc((size_t)2 * NNODE * 4);   // deg | rowcnt (single memset)
    int*      deg    = cnt;
    int*      rowcnt = cnt + NNODE;
    int*      colsA  = (int*)alloc((size_t)NNODE * KCAP * 4);
    float*    wAr    = (float*)alloc((size_t)NNODE * KCAP * 4);
    float*    rsum   = (float*)alloc((size_t)NNODE * 4);
    _Float16* xh     = (_Float16*)alloc((size_t)NNODE * 512 * 2);
    _Float16* w1T    = (_Float16*)alloc((size_t)512 * NHID * 2);
    _Float16* w2T    = (_Float16*)alloc((size_t)NHID * NHID * 2);
    _Float16* X1     = (_Float16*)alloc((size_t)NNODE * NHID * 2);   // also X2
    _Float16* Hh     = (_Float16*)alloc((size_t)NNODE * NHID * 2);
    int*      nbr    = (int*)alloc((size_t)NNODE * RCAP * 4);

    const int nscat = (E + NNODE + 255) / 256;

    hipMemsetAsync(cnt, 0, (size_t)2 * NNODE * 4, stream);
    k_prep_scatter<<<PREPB + nscat, 256, 0, stream>>>(x, xh, W1, w1T, W2, w2T,
                                                      ei, rowcnt, nbr, deg, E);
    k_gemm1_dedup<<<512 + NNODE / 2, 256, 0, stream>>>(xh, w1T, X1, nbr, rowcnt, deg,
                                                       colsA, wAr, rsum);
    k_medoid<<<NNODE / 4, 256, 0, stream>>>(X1, b1, nullptr, Hh, colsA, wAr, rsum, 1);
    k_gemm2<<<dim3(NNODE / 64, NHID / 64), 256, 0, stream>>>(Hh, w2T, X1);
    k_medoid<<<NNODE / 4, 256, 0, stream>>>(X1, b2, out, nullptr, colsA, wAr, rsum, 0);
}

// Round 9
// 261.660 us; speedup vs baseline: 1.2117x; 1.2117x over previous
//
#include <hip/hip_runtime.h>

typedef _Float16 half4 __attribute__((ext_vector_type(4)));
typedef _Float16 half8 __attribute__((ext_vector_type(8)));
typedef float f32x4 __attribute__((ext_vector_type(4)));

#define NNODE 8192
#define NHID  256
#define RCAP  128
#define KCAP  64
#define GLS   72    // gemm lds row stride (fp16): 144B = 9 quads, conflict-free
#define SK2   68    // medoid 2-wave lds row stride (fp16): 136B; 2-way free on writes

struct SmemGemm  { _Float16 sA[64][GLS]; _Float16 sB[64][GLS]; };
struct SmemDedup { int lc[2][RCAP]; float lw[2][RCAP]; unsigned char kp[2][RCAP];
                   int cw[2][2]; float rw[2][2]; };
// 2-wave medoid: 64 rows x 64 dims staged per phase (4 phases). ~10KB/node.
// s_red aliases sh (only live after last sh read; barrier-guarded).
struct SmemMedoid2 {
    union {
        _Float16 sh[64][SK2];     // 8704 B
        float s_red[2][288];      // 2304 B
    };
    float s_a[64]; float s_sq[64]; float s_cpart[3][64];
};

// ---------------------------------------------------------------- GEMM tile body (fp16 A, fp16 BT)
__device__ __forceinline__ void gemm_body(
    char* smraw, const _Float16* __restrict__ Ahi, const _Float16* __restrict__ BT,
    _Float16* __restrict__ Chi, int K, int bm, int bn) {
    SmemGemm& sm = *(SmemGemm*)smraw;
    const int t = threadIdx.x;
    const int lane = t & 63, L15 = lane & 15, q = lane >> 4;
    const int w = t >> 6, wr = w >> 1, wc = w & 1;
    f32x4 acc[2][2];
#pragma unroll
    for (int a = 0; a < 2; ++a)
#pragma unroll
        for (int b2 = 0; b2 < 2; ++b2) acc[a][b2] = (f32x4){0.f, 0.f, 0.f, 0.f};

    for (int k0 = 0; k0 < K; k0 += 64) {
#pragma unroll
        for (int i = 0; i < 2; ++i) {
            int row = i * 32 + (t >> 3), ch = t & 7;
            *(half8*)&sm.sA[row][ch * 8] =
                *(const half8*)(Ahi + (size_t)(bm + row) * K + k0 + ch * 8);
            *(half8*)&sm.sB[row][ch * 8] =
                *(const half8*)(BT + (size_t)(bn + row) * K + k0 + ch * 8);
        }
        __syncthreads();
#pragma unroll
        for (int ks = 0; ks < 2; ++ks) {
            const int ko = ks * 32 + q * 8;
            half8 ah[2], bh[2];
#pragma unroll
            for (int tr = 0; tr < 2; ++tr)
                ah[tr] = *(const half8*)&sm.sA[32 * wr + 16 * tr + L15][ko];
#pragma unroll
            for (int tc = 0; tc < 2; ++tc)
                bh[tc] = *(const half8*)&sm.sB[32 * wc + 16 * tc + L15][ko];
#pragma unroll
            for (int tr = 0; tr < 2; ++tr)
#pragma unroll
                for (int tc = 0; tc < 2; ++tc)
                    acc[tr][tc] = __builtin_amdgcn_mfma_f32_16x16x32_f16(ah[tr], bh[tc], acc[tr][tc], 0, 0, 0);
        }
        __syncthreads();
    }
#pragma unroll
    for (int tr = 0; tr < 2; ++tr)
#pragma unroll
        for (int tc = 0; tc < 2; ++tc)
#pragma unroll
            for (int r = 0; r < 4; ++r) {
                int rowg = bm + 32 * wr + 16 * tr + q * 4 + r;
                int colg = bn + 32 * wc + 16 * tc + L15;
                Chi[(size_t)rowg * NHID + colg] = (_Float16)acc[tr][tc][r];
            }
}

// ---------------------------------------------------------------- dedup body (2 rows per call)
__device__ __forceinline__ void dedup_body(
    char* smraw, const int* __restrict__ nbr, const int* __restrict__ rowcnt,
    const int* __restrict__ deg, int* __restrict__ cols, float* __restrict__ wout,
    float* __restrict__ rsum, int grp) {
    SmemDedup& sm = *(SmemDedup*)smraw;
    const int t = threadIdx.x;
    const int half = t >> 7, st = t & 127;
    const int wid = st >> 6, lane = t & 63;
    const int r = grp * 2 + half;
    int n = rowcnt[r]; if (n > RCAP) n = RCAP;
    if (st < n) sm.lc[half][st] = nbr[r * RCAP + st];
    __syncthreads();
    float dr = 1.f / sqrtf((float)deg[r]);
    bool keep = false; float wv = 0.f;
    if (st < n) {
        int c = sm.lc[half][st];
        int mult = 0; bool first = true;
        for (int i = 0; i < n; ++i) {
            int ci = sm.lc[half][i];
            if (ci == c) { mult++; if (i < st) first = false; }
        }
        keep = first;
        if (first) wv = (float)mult * dr * (1.f / sqrtf((float)deg[c]));
    }
    sm.kp[half][st] = keep ? 1 : 0; sm.lw[half][st] = wv;
    float rv = wv;
#pragma unroll
    for (int d = 1; d < 64; d <<= 1) rv += __shfl_xor(rv, d, 64);
    unsigned long long b = __ballot(keep);
    int pre = __popcll(b & ((1ull << lane) - 1ull));
    int cw = __popcll(b);
    if (lane == 0) { sm.cw[half][wid] = cw; sm.rw[half][wid] = rv; }
    __syncthreads();
    int total = sm.cw[half][0] + sm.cw[half][1];
    if (st == 0) rsum[r] = sm.rw[half][0] + sm.rw[half][1];
    const int base = r * KCAP;
    if (total <= KCAP) {
        int off = (wid ? sm.cw[half][0] : 0) + pre;
        if (keep) { cols[base + off] = sm.lc[half][st]; wout[base + off] = wv; }
        for (int m = total + st; m < KCAP; m += 128) { cols[base + m] = r; wout[base + m] = 0.f; }
    } else if (st == 0) {
        for (int s = 0; s < KCAP; ++s) {
            int best = -1;
            for (int i = 0; i < n; ++i) {
                if (!sm.kp[half][i]) continue;
                if (best < 0 || sm.lw[half][i] > sm.lw[half][best] ||
                    (sm.lw[half][i] == sm.lw[half][best] && sm.lc[half][i] < sm.lc[half][best])) best = i;
            }
            cols[base + s] = sm.lc[half][best]; wout[base + s] = sm.lw[half][best]; sm.kp[half][best] = 0;
        }
    }
}

#define MFMA16(a, b, c) __builtin_amdgcn_mfma_f32_16x16x32_f16((a), (b), (c), 0, 0, 0)

// ================================================================ D3/D5: medoid — 2 waves per node, 128-thread blocks
// Gram symmetry split across 2 waves (acc = 24 VGPR/thread):
//   wave0: diag rows0-31 (accd 2x2) + off rows0-31 x cols32-47 (acco, B = rows32-47)
//   wave1: diag rows32-63            + off rows0-31 x cols48-63 (B = its diag ah1)
// Mirror quadrants via dist-symmetry transpose (R2-verified scheme).
// cpart slots: s0 = diag0[0-31] | off0-fwd[32-47] | off1-fwd[48-63]
//              s1 = off0-T[0-31] | diag1[32-63]
//              s2 = off1-T[0-31] | zeros[32-63]
// 12 blocks/CU (launch_bounds(128,6): 24 waves, VGPR cap 85 — anti-spill headroom).
__global__ __launch_bounds__(128, 6) void k_medoid(
    const _Float16* __restrict__ X, const float* __restrict__ bias,
    float* __restrict__ OutF, _Float16* __restrict__ OutHi,
    const int* __restrict__ cols, const float* __restrict__ wts,
    const float* __restrict__ rsum, int writeH) {
    __shared__ __align__(16) SmemMedoid2 sm;
    const int t = threadIdx.x;                 // 0..127
    const int u = t >> 6, lane = t & 63;       // wave-in-node, lane
    const int L15 = lane & 15, q = lane >> 4;
    const int node = blockIdx.x;
    const int rb = u * 32;

    const int   base = node * KCAP;
    const int   cid  = cols[base + lane];      // each wave holds full cid[0..63]
    const float aj   = wts[base + lane];
    const float rs   = rsum[node];

    sm.s_a[lane] = aj;                         // both waves write identical values
    if (lane >= 32) sm.s_cpart[2][lane] = 0.f; // zero unused transpose-slot rows

    // staging map: rowslot = t>>3 (wave0: 0-7, wave1: 8-15), ch = t&7
    const int rowslot = t >> 3, ch = t & 7;
    const _Float16* rbase[4];
#pragma unroll
    for (int i = 0; i < 4; ++i) {
        int cr = __shfl(cid, i * 16 + rowslot, 64);
        rbase[i] = X + ((size_t)cr << 8) + ch * 8;
    }

    // ---- stage phase 0 (dims 0..63)
#pragma unroll
    for (int i = 0; i < 4; ++i)
        *(half8*)&sm.sh[i * 16 + rowslot][ch * 8] = *(const half8*)rbase[i];
    __syncthreads();

    f32x4 accd[2][2]; f32x4 acco[2];
#pragma unroll
    for (int a = 0; a < 2; ++a) {
        acco[a] = (f32x4){0.f, 0.f, 0.f, 0.f};
#pragma unroll
        for (int b = 0; b < 2; ++b) accd[a][b] = (f32x4){0.f, 0.f, 0.f, 0.f};
    }

#pragma unroll
    for (int ph = 0; ph < 4; ++ph) {
        // issue next-phase gather early (T14): hides under this phase's MFMA
        half8 gnext[4];
        if (ph < 3) {
#pragma unroll
            for (int i = 0; i < 4; ++i)
                gnext[i] = *(const half8*)(rbase[i] + (ph + 1) * 64);
        }
#pragma unroll
        for (int ks = 0; ks < 2; ++ks) {
            const int ko = ks * 32 + q * 8;
            half8 ah0 = *(const half8*)&sm.sh[rb + L15][ko];
            half8 ah1 = *(const half8*)&sm.sh[rb + 16 + L15][ko];
            accd[0][0] = MFMA16(ah0, ah0, accd[0][0]);
            accd[0][1] = MFMA16(ah0, ah1, accd[0][1]);
            accd[1][0] = MFMA16(ah1, ah0, accd[1][0]);
            accd[1][1] = MFMA16(ah1, ah1, accd[1][1]);
            if (u == 0) {
                half8 bh = *(const half8*)&sm.sh[32 + L15][ko];
                acco[0] = MFMA16(ah0, bh, acco[0]);
                acco[1] = MFMA16(ah1, bh, acco[1]);
            } else {
                half8 c0 = *(const half8*)&sm.sh[L15][ko];
                half8 c1 = *(const half8*)&sm.sh[16 + L15][ko];
                acco[0] = MFMA16(c0, ah1, acco[0]);
                acco[1] = MFMA16(c1, ah1, acco[1]);
            }
        }
        if (ph < 3) {
            __syncthreads();   // WAR: all reads of sh done before overwrite
#pragma unroll
            for (int i = 0; i < 4; ++i)
                *(half8*)&sm.sh[i * 16 + rowslot][ch * 8] = gnext[i];
            __syncthreads();   // RAW
        }
    }
    // sh holds dims 192..255 for the epilogue

    // ---- diagonal extraction: wave0 -> sq[0-31], wave1 -> sq[32-63]
#pragma unroll
    for (int tr = 0; tr < 2; ++tr)
#pragma unroll
        for (int r = 0; r < 4; ++r)
            if (L15 == q * 4 + r) sm.s_sq[rb + 16 * tr + L15] = accd[tr][tr][r];
    __syncthreads();

    // ---- diag-quadrant forward cost -> cpart[u][rb + 16tc + L15]
    {
        f32x4 sq4[2], a4[2];
#pragma unroll
        for (int tr = 0; tr < 2; ++tr) {
            sq4[tr] = *(const f32x4*)&sm.s_sq[rb + 16 * tr + 4 * q];
            a4[tr]  = *(const f32x4*)&sm.s_a [rb + 16 * tr + 4 * q];
        }
#pragma unroll
        for (int tc = 0; tc < 2; ++tc) {
            const int colg = rb + 16 * tc + L15;
            const float sqc = sm.s_sq[colg];
            float pj = 0.f;
#pragma unroll
            for (int tr = 0; tr < 2; ++tr)
#pragma unroll
                for (int r = 0; r < 4; ++r) {
                    float d2 = sq4[tr][r] + sqc - 2.f * accd[tr][tc][r];
                    float dist = d2 > 0.f ? __builtin_amdgcn_sqrtf(d2) : 0.f;
                    pj = fmaf(a4[tr][r], dist, pj);
                }
            pj += __shfl_xor(pj, 16, 64);
            pj += __shfl_xor(pj, 32, 64);
            if (q == 0) sm.s_cpart[u][colg] = pj;   // u==0: cols 0-31; u==1: cols 32-63
        }
    }

    // ---- off-tile forward + transpose (A rows always 0-31)
    {
        const int colO = (u == 0 ? 32 : 48) + L15;
        const float sqcO = sm.s_sq[colO];
        const float acO  = sm.s_a[colO];
        f32x4 sq4o[2], a4o[2];
#pragma unroll
        for (int tr = 0; tr < 2; ++tr) {
            sq4o[tr] = *(const f32x4*)&sm.s_sq[16 * tr + 4 * q];
            a4o[tr]  = *(const f32x4*)&sm.s_a [16 * tr + 4 * q];
        }
        float pj = 0.f;
        float pt[2][4];
#pragma unroll
        for (int tr = 0; tr < 2; ++tr)
#pragma unroll
            for (int r = 0; r < 4; ++r) {
                float d2 = sq4o[tr][r] + sqcO - 2.f * acco[tr][r];
                float dist = d2 > 0.f ? __builtin_amdgcn_sqrtf(d2) : 0.f;
                pj = fmaf(a4o[tr][r], dist, pj);   // a[row 0-31]*dist -> cst[colO]
                pt[tr][r] = acO * dist;            // a[colO]*dist -> cst[row 0-31]
            }
        pj += __shfl_xor(pj, 16, 64);
        pj += __shfl_xor(pj, 32, 64);
        if (q == 0) sm.s_cpart[0][colO] = pj;      // disjoint from diag slots
#pragma unroll
        for (int tr = 0; tr < 2; ++tr)
#pragma unroll
            for (int r = 0; r < 4; ++r) {
                float v = pt[tr][r];
                v += __shfl_xor(v, 1, 64);
                v += __shfl_xor(v, 2, 64);
                v += __shfl_xor(v, 4, 64);
                v += __shfl_xor(v, 8, 64);
                pt[tr][r] = v;
            }
        if (L15 == 0) {
#pragma unroll
            for (int tr = 0; tr < 2; ++tr)
#pragma unroll
                for (int r = 0; r < 4; ++r)
                    sm.s_cpart[1 + u][16 * tr + 4 * q + r] = pt[tr][r];
        }
    }
    __syncthreads();

    // ---- softmax (redundant in both waves; u_own stays in-register)
    float u_own;
    {
        float c = sm.s_cpart[0][lane] + sm.s_cpart[1][lane] + sm.s_cpart[2][lane];
        bool valid = aj > 0.f;
        float cv = valid ? c : 3.4e38f;
        float mn = cv;
#pragma unroll
        for (int d = 1; d < 64; d <<= 1) mn = fminf(mn, __shfl_xor(mn, d, 64));
        float e = valid ? __expf(mn - c) * aj : 0.f;
        float s = e;
#pragma unroll
        for (int d = 1; d < 64; d <<= 1) s += __shfl_xor(s, d, 64);
        u_own = e * (rs / s);
    }

    // ---- weighted-sum epilogue: dims 0..191 global (L2-hot), 192..255 from sh
    const int oct = t & 31, jg = t >> 5;   // dims oct*8..+8, rows jg*16..+15
    float o[8] = {0.f, 0.f, 0.f, 0.f, 0.f, 0.f, 0.f, 0.f};
#pragma unroll
    for (int jj = 0; jj < 16; ++jj) {
        int j = jg * 16 + jj;
        float uv = __shfl(u_own, j, 64);
        int  cj2 = __shfl(cid, j, 64);
        half8 xv;
        if (oct < 24) xv = *(const half8*)(X + ((size_t)cj2 << 8) + oct * 8);
        else          xv = *(const half8*)&sm.sh[j][(oct - 24) * 8];
#pragma unroll
        for (int e2 = 0; e2 < 8; ++e2) o[e2] = fmaf(uv, (float)xv[e2], o[e2]);
    }
#pragma unroll
    for (int e2 = 0; e2 < 8; ++e2) o[e2] += __shfl_xor(o[e2], 32, 64);
    __syncthreads();   // sh reads drained before writing aliased s_red
    if (lane < 32) {
#pragma unroll
        for (int e2 = 0; e2 < 8; ++e2) sm.s_red[u][9 * oct + e2] = o[e2];
    }
    __syncthreads();
#pragma unroll
    for (int h = 0; h < 2; ++h) {
        int d = h * 128 + t;
        int idx = 9 * (d >> 3) + (d & 7);
        float res = fmaxf(sm.s_red[0][idx] + sm.s_red[1][idx] + bias[d], 0.f);
        size_t oi = (size_t)node * NHID + d;
        if (writeH) OutHi[oi] = (_Float16)res;
        else        OutF[oi] = res;
    }
}

// ================================================================ D1: prep (xh, w1T, w2T) ∥ edge scatter
#define PREPB 512
__global__ __launch_bounds__(256) void k_prep_scatter(
    const float* __restrict__ x, _Float16* __restrict__ xh,
    const float* __restrict__ W1, _Float16* __restrict__ w1T,
    const float* __restrict__ W2, _Float16* __restrict__ w2T,
    const void* edges, int* rowcnt, int* nbr, int* deg, int E) {
    const int t = threadIdx.x;
    if ((int)blockIdx.x < PREPB) {
        const int gid = blockIdx.x * 256 + t, nthr = PREPB * 256;
        for (int i = gid; i < NNODE * 512 / 4; i += nthr) {
            float4 v = ((const float4*)x)[i];
            half4 h;
            h[0] = (_Float16)v.x; h[1] = (_Float16)v.y;
            h[2] = (_Float16)v.z; h[3] = (_Float16)v.w;
            *(half4*)&xh[4 * (size_t)i] = h;
        }
        for (int i = gid; i < 512 * NHID; i += nthr) {
            int k = i >> 8, n = i & 255;
            w1T[(size_t)n * 512 + k] = (_Float16)W1[i];
        }
        for (int i = gid; i < NHID * NHID; i += nthr) {
            int k = i >> 8, n = i & 255;
            w2T[(size_t)n * 256 + k] = (_Float16)W2[i];
        }
    } else {
        __shared__ int sflag;
        if (t < 64) {   // per-block dtype probe (L2-hot)
            const long long* e = (const long long*)edges;
            long long v = e[t];
            unsigned long long bad = __ballot(v < 0 || v >= (long long)NNODE);
            if (t == 0) sflag = (bad == 0) ? 1 : 0;
        }
        __syncthreads();
        const int fl = sflag;
        int i = ((int)blockIdx.x - PREPB) * 256 + t;
        if (i >= E + NNODE) return;
        int r, c;
        if (i < E) {
            if (fl) {
                const long long* e = (const long long*)edges;
                r = (int)e[i]; c = (int)e[E + i];
            } else {
                const int* e = (const int*)edges;
                r = e[i]; c = e[E + i];
            }
        } else { r = i - E; c = r; }   // self loop
        int pos = atomicAdd(&rowcnt[r], 1);
        if (pos < RCAP) nbr[r * RCAP + pos] = c;
        atomicAdd(&deg[c], 1);
    }
}

// ================================================================ D2: gemm1 (blocks 0..511) ∥ dedup
__global__ __launch_bounds__(256) void k_gemm1_dedup(
    const _Float16* __restrict__ xh, const _Float16* __restrict__ w1T,
    _Float16* __restrict__ X1,
    const int* __restrict__ nbr, const int* __restrict__ rowcnt,
    const int* __restrict__ deg,
    int* __restrict__ cols, float* __restrict__ wA, float* __restrict__ rsum) {
    __shared__ __align__(16) char smem[sizeof(SmemGemm)];
    if ((int)blockIdx.x < 512) {
        int g = blockIdx.x;
        gemm_body(smem, xh, w1T, X1, 512, (g >> 2) * 64, (g & 3) * 64);
    } else {
        dedup_body(smem, nbr, rowcnt, deg, cols, wA, rsum, (int)blockIdx.x - 512);
    }
}

// ================================================================ D4: gemm layer 2
__global__ __launch_bounds__(256) void k_gemm2(
    const _Float16* __restrict__ Hh, const _Float16* __restrict__ w2T,
    _Float16* __restrict__ X2) {
    __shared__ __align__(16) char smem[sizeof(SmemGemm)];
    gemm_body(smem, Hh, w2T, X2, 256, blockIdx.x * 64, blockIdx.y * 64);
}

// ================================================================ launch
extern "C" void kernel_launch(void* const* d_in, const int* in_sizes, int n_in,
                              void* d_out, int out_size, void* d_ws, size_t ws_size,
                              hipStream_t stream) {
    const float* x  = (const float*)d_in[0];
    const void*  ei = d_in[1];
    const float* W1 = (const float*)d_in[2];
    const float* b1 = (const float*)d_in[3];
    const float* W2 = (const float*)d_in[4];
    const float* b2 = (const float*)d_in[5];
    float* out = (float*)d_out;
    const int E = in_sizes[1] / 2;

    char* p = (char*)d_ws;
    auto alloc = [&](size_t bytes) { char* q = p; p += (bytes + 255) & ~(size_t)255; return q; };
    int*      cnt    = (int*)alloc((size_t)2 * NNODE * 4);   // deg | rowcnt (single memset)
    int*      deg    = cnt;
    int*      rowcnt = cnt + NNODE;
    int*      colsA  = (int*)alloc((size_t)NNODE * KCAP * 4);
    float*    wAr    = (float*)alloc((size_t)NNODE * KCAP * 4);
    float*    rsum   = (float*)alloc((size_t)NNODE * 4);
    _Float16* xh     = (_Float16*)alloc((size_t)NNODE * 512 * 2);
    _Float16* w1T    = (_Float16*)alloc((size_t)512 * NHID * 2);
    _Float16* w2T    = (_Float16*)alloc((size_t)NHID * NHID * 2);
    _Float16* X1     = (_Float16*)alloc((size_t)NNODE * NHID * 2);   // also X2
    _Float16* Hh     = (_Float16*)alloc((size_t)NNODE * NHID * 2);
    int*      nbr    = (int*)alloc((size_t)NNODE * RCAP * 4);

    const int nscat = (E + NNODE + 255) / 256;

    hipMemsetAsync(cnt, 0, (size_t)2 * NNODE * 4, stream);
    k_prep_scatter<<<PREPB + nscat, 256, 0, stream>>>(x, xh, W1, w1T, W2, w2T,
                                                      ei, rowcnt, nbr, deg, E);
    k_gemm1_dedup<<<512 + NNODE / 2, 256, 0, stream>>>(xh, w1T, X1, nbr, rowcnt, deg,
                                                       colsA, wAr, rsum);
    k_medoid<<<NNODE, 128, 0, stream>>>(X1, b1, nullptr, Hh, colsA, wAr, rsum, 1);
    k_gemm2<<<dim3(NNODE / 64, NHID / 64), 256, 0, stream>>>(Hh, w2T, X1);
    k_medoid<<<NNODE, 128, 0, stream>>>(X1, b2, out, nullptr, colsA, wAr, rsum, 0);
}

// Round 10
// 196.179 us; speedup vs baseline: 1.6162x; 1.3338x over previous
//
#include <hip/hip_runtime.h>

typedef _Float16 half4 __attribute__((ext_vector_type(4)));
typedef _Float16 half8 __attribute__((ext_vector_type(8)));
typedef float f32x4 __attribute__((ext_vector_type(4)));

#define NNODE 8192
#define NHID  256
#define RCAP  128
#define KCAP  64
#define GLS   72    // gemm lds row stride (fp16): 144B = 9 quads, conflict-free
#define SK    136   // medoid lds row stride (fp16): 272B = 17 quads, conflict-free

struct SmemGemm  { _Float16 sA[64][GLS]; _Float16 sB[64][GLS]; };
struct SmemDedup { int lc[2][RCAP]; float lw[2][RCAP]; unsigned char kp[2][RCAP];
                   int cw[2][2]; float rw[2][2]; };
struct SmemMedoid {
    // s_red aliases sh (s_red only live after last sh read; one barrier guards it).
    // 19.2KB total -> 8 blocks/CU (LDS cap 160KB).
    union {
        _Float16 sh[64][SK];
        float s_red[4][288];
    };
    float s_a[64]; float s_sq[64]; float s_cpart[3][64]; float s_u[64];
    int s_cols[64]; float s_rsum;
};

// ---------------------------------------------------------------- GEMM tile body (fp16 A, fp16 BT)
__device__ __forceinline__ void gemm_body(
    char* smraw, const _Float16* __restrict__ Ahi, const _Float16* __restrict__ BT,
    _Float16* __restrict__ Chi, int K, int bm, int bn) {
    SmemGemm& sm = *(SmemGemm*)smraw;
    const int t = threadIdx.x;
    const int lane = t & 63, L15 = lane & 15, q = lane >> 4;
    const int w = t >> 6, wr = w >> 1, wc = w & 1;
    f32x4 acc[2][2];
#pragma unroll
    for (int a = 0; a < 2; ++a)
#pragma unroll
        for (int b2 = 0; b2 < 2; ++b2) acc[a][b2] = (f32x4){0.f, 0.f, 0.f, 0.f};

    for (int k0 = 0; k0 < K; k0 += 64) {
#pragma unroll
        for (int i = 0; i < 2; ++i) {
            int row = i * 32 + (t >> 3), ch = t & 7;
            *(half8*)&sm.sA[row][ch * 8] =
                *(const half8*)(Ahi + (size_t)(bm + row) * K + k0 + ch * 8);
            *(half8*)&sm.sB[row][ch * 8] =
                *(const half8*)(BT + (size_t)(bn + row) * K + k0 + ch * 8);
        }
        __syncthreads();
#pragma unroll
        for (int ks = 0; ks < 2; ++ks) {
            const int ko = ks * 32 + q * 8;
            half8 ah[2], bh[2];
#pragma unroll
            for (int tr = 0; tr < 2; ++tr)
                ah[tr] = *(const half8*)&sm.sA[32 * wr + 16 * tr + L15][ko];
#pragma unroll
            for (int tc = 0; tc < 2; ++tc)
                bh[tc] = *(const half8*)&sm.sB[32 * wc + 16 * tc + L15][ko];
#pragma unroll
            for (int tr = 0; tr < 2; ++tr)
#pragma unroll
                for (int tc = 0; tc < 2; ++tc)
                    acc[tr][tc] = __builtin_amdgcn_mfma_f32_16x16x32_f16(ah[tr], bh[tc], acc[tr][tc], 0, 0, 0);
        }
        __syncthreads();
    }
#pragma unroll
    for (int tr = 0; tr < 2; ++tr)
#pragma unroll
        for (int tc = 0; tc < 2; ++tc)
#pragma unroll
            for (int r = 0; r < 4; ++r) {
                int rowg = bm + 32 * wr + 16 * tr + q * 4 + r;
                int colg = bn + 32 * wc + 16 * tc + L15;
                Chi[(size_t)rowg * NHID + colg] = (_Float16)acc[tr][tc][r];
            }
}

// ---------------------------------------------------------------- dedup body (2 rows per call)
__device__ __forceinline__ void dedup_body(
    char* smraw, const int* __restrict__ nbr, const int* __restrict__ rowcnt,
    const int* __restrict__ deg, int* __restrict__ cols, float* __restrict__ wout,
    float* __restrict__ rsum, int grp) {
    SmemDedup& sm = *(SmemDedup*)smraw;
    const int t = threadIdx.x;
    const int half = t >> 7, st = t & 127;
    const int wid = st >> 6, lane = t & 63;
    const int r = grp * 2 + half;
    int n = rowcnt[r]; if (n > RCAP) n = RCAP;
    if (st < n) sm.lc[half][st] = nbr[r * RCAP + st];
    __syncthreads();
    float dr = 1.f / sqrtf((float)deg[r]);
    bool keep = false; float wv = 0.f;
    if (st < n) {
        int c = sm.lc[half][st];
        int mult = 0; bool first = true;
        for (int i = 0; i < n; ++i) {
            int ci = sm.lc[half][i];
            if (ci == c) { mult++; if (i < st) first = false; }
        }
        keep = first;
        if (first) wv = (float)mult * dr * (1.f / sqrtf((float)deg[c]));
    }
    sm.kp[half][st] = keep ? 1 : 0; sm.lw[half][st] = wv;
    float rv = wv;
#pragma unroll
    for (int d = 1; d < 64; d <<= 1) rv += __shfl_xor(rv, d, 64);
    unsigned long long b = __ballot(keep);
    int pre = __popcll(b & ((1ull << lane) - 1ull));
    int cw = __popcll(b);
    if (lane == 0) { sm.cw[half][wid] = cw; sm.rw[half][wid] = rv; }
    __syncthreads();
    int total = sm.cw[half][0] + sm.cw[half][1];
    if (st == 0) rsum[r] = sm.rw[half][0] + sm.rw[half][1];
    const int base = r * KCAP;
    if (total <= KCAP) {
        int off = (wid ? sm.cw[half][0] : 0) + pre;
        if (keep) { cols[base + off] = sm.lc[half][st]; wout[base + off] = wv; }
        for (int m = total + st; m < KCAP; m += 128) { cols[base + m] = r; wout[base + m] = 0.f; }
    } else if (st == 0) {
        for (int s = 0; s < KCAP; ++s) {
            int best = -1;
            for (int i = 0; i < n; ++i) {
                if (!sm.kp[half][i]) continue;
                if (best < 0 || sm.lw[half][i] > sm.lw[half][best] ||
                    (sm.lw[half][i] == sm.lw[half][best] && sm.lc[half][i] < sm.lc[half][best])) best = i;
            }
            cols[base + s] = sm.lc[half][best]; wout[base + s] = sm.lw[half][best]; sm.kp[half][best] = 0;
        }
    }
}

// ---------------------------------------------------------------- medoid core (s_cols/s_a/s_rsum pre-loaded)
// R2-verified Gram symmetry layout (best measured: 45.6us, no spill):
//   w0: rows 0-31  x cols 0-31   (bh==ah, 2 reads/ks, 4 MFMA)
//   w3: rows 32-63 x cols 32-63  (bh==ah)
//   w1: rows 0-31  x cols 32-47  (3 reads/ks, 2 MFMA) + transposed contribution
//   w2: rows 0-31  x cols 48-63  (3 reads/ks, 2 MFMA) + transposed contribution
// Mirror quadrant (rows 32-63 x cols 0-31) recovered via dist symmetry.
// NOTE (4x-spill lesson, R3/R4/R8/R9): do NOT hold gathered half8 tiles in
// registers across the cost/softmax region — the allocator spills to scratch
// (WRITE_SIZE balloons to ~90-220MB). g0/g1 die at their staging writes.
__device__ __forceinline__ void medoid_core(
    SmemMedoid& sm, const _Float16* __restrict__ Xhi, float bv,
    float* __restrict__ OutF, _Float16* __restrict__ OutHi, int node, int writeH) {
    const int t = threadIdx.x;
    const int w = t >> 6, lane = t & 63;
    const int L15 = lane & 15, q = lane >> 4;
    const bool diagw = (w == 0 || w == 3);
    const int rb = (w == 3) ? 32 : 0;              // row base (ah rows)
    const int cb = (w == 1) ? 32 : 48;             // off-diag col base (bh row)

    f32x4 acc[2][2];
#pragma unroll
    for (int a = 0; a < 2; ++a)
#pragma unroll
        for (int b = 0; b < 2; ++b) acc[a][b] = (f32x4){0.f, 0.f, 0.f, 0.f};

    const int ch = t & 15, rr = t >> 4;
    const _Float16* rbase[4];
#pragma unroll
    for (int i = 0; i < 4; ++i)
        rbase[i] = Xhi + ((size_t)sm.s_cols[i * 16 + rr] << 8) + ch * 8;

    // ---- phase-0 gather (dims 0..127)
    half8 g0[4];
#pragma unroll
    for (int i = 0; i < 4; ++i) g0[i] = *(const half8*)rbase[i];
#pragma unroll
    for (int i = 0; i < 4; ++i) *(half8*)&sm.sh[i * 16 + rr][ch * 8] = g0[i];
    __syncthreads();

    // ---- issue phase-1 gather NOW; latency hides under phase-0 MFMA (T14)
    half8 g1[4];
#pragma unroll
    for (int i = 0; i < 4; ++i) g1[i] = *(const half8*)(rbase[i] + 128);

    // ---- phase-0 MFMA
#pragma unroll
    for (int ks = 0; ks < 4; ++ks) {
        const int ko = ks * 32 + q * 8;
        half8 ah[2];
        ah[0] = *(const half8*)&sm.sh[rb + L15][ko];
        ah[1] = *(const half8*)&sm.sh[rb + 16 + L15][ko];
        if (diagw) {
#pragma unroll
            for (int tr = 0; tr < 2; ++tr)
#pragma unroll
                for (int tc = 0; tc < 2; ++tc)
                    acc[tr][tc] = __builtin_amdgcn_mfma_f32_16x16x32_f16(ah[tr], ah[tc], acc[tr][tc], 0, 0, 0);
        } else {
            half8 bh = *(const half8*)&sm.sh[cb + L15][ko];
            acc[0][0] = __builtin_amdgcn_mfma_f32_16x16x32_f16(ah[0], bh, acc[0][0], 0, 0, 0);
            acc[1][0] = __builtin_amdgcn_mfma_f32_16x16x32_f16(ah[1], bh, acc[1][0], 0, 0, 0);
        }
    }
    __syncthreads();

    // ---- phase-1 write + MFMA
#pragma unroll
    for (int i = 0; i < 4; ++i) *(half8*)&sm.sh[i * 16 + rr][ch * 8] = g1[i];
    __syncthreads();
#pragma unroll
    for (int ks = 0; ks < 4; ++ks) {
        const int ko = ks * 32 + q * 8;
        half8 ah[2];
        ah[0] = *(const half8*)&sm.sh[rb + L15][ko];
        ah[1] = *(const half8*)&sm.sh[rb + 16 + L15][ko];
        if (diagw) {
#pragma unroll
            for (int tr = 0; tr < 2; ++tr)
#pragma unroll
                for (int tc = 0; tc < 2; ++tc)
                    acc[tr][tc] = __builtin_amdgcn_mfma_f32_16x16x32_f16(ah[tr], ah[tc], acc[tr][tc], 0, 0, 0);
        } else {
            half8 bh = *(const half8*)&sm.sh[cb + L15][ko];
            acc[0][0] = __builtin_amdgcn_mfma_f32_16x16x32_f16(ah[0], bh, acc[0][0], 0, 0, 0);
            acc[1][0] = __builtin_amdgcn_mfma_f32_16x16x32_f16(ah[1], bh, acc[1][0], 0, 0, 0);
        }
    }
    // sm.sh holds dims 128..255 for the epilogue

    // ---- diagonal extraction (only diag waves hold diag tiles)
    if (diagw) {
#pragma unroll
        for (int tr = 0; tr < 2; ++tr)
#pragma unroll
            for (int r = 0; r < 4; ++r)
                if (L15 == q * 4 + r) sm.s_sq[rb + 16 * tr + L15] = acc[tr][tr][r];
    }
    __syncthreads();

    f32x4 sq4[2], a4[2];
#pragma unroll
    for (int tr = 0; tr < 2; ++tr) {
        sq4[tr] = *(const f32x4*)&sm.s_sq[rb + 16 * tr + 4 * q];
        a4[tr]  = *(const f32x4*)&sm.s_a [rb + 16 * tr + 4 * q];
    }

    if (diagw) {
        const int slot = (w == 0) ? 0 : 1;
#pragma unroll
        for (int tc = 0; tc < 2; ++tc) {
            const int colg = rb + 16 * tc + L15;
            const float sqc = sm.s_sq[colg];
            float pj = 0.f;
#pragma unroll
            for (int tr = 0; tr < 2; ++tr)
#pragma unroll
                for (int r = 0; r < 4; ++r) {
                    float d2 = sq4[tr][r] + sqc - 2.f * acc[tr][tc][r];
                    float dist = d2 > 0.f ? __builtin_amdgcn_sqrtf(d2) : 0.f;
                    pj = fmaf(a4[tr][r], dist, pj);
                }
            pj += __shfl_xor(pj, 16, 64);
            pj += __shfl_xor(pj, 32, 64);
            if (q == 0) sm.s_cpart[slot][colg] = pj;
        }
    } else {
        const int colg = cb + L15;
        const float sqc = sm.s_sq[colg];
        const float ac  = sm.s_a[colg];
        float pj = 0.f;
        float pt[2][4];
#pragma unroll
        for (int tr = 0; tr < 2; ++tr)
#pragma unroll
            for (int r = 0; r < 4; ++r) {
                float d2 = sq4[tr][r] + sqc - 2.f * acc[tr][0][r];
                float dist = d2 > 0.f ? __builtin_amdgcn_sqrtf(d2) : 0.f;
                pj = fmaf(a4[tr][r], dist, pj);     // a[row]*dist -> c[col]
                pt[tr][r] = ac * dist;              // a[col]*dist -> c[row] (transpose)
            }
        pj += __shfl_xor(pj, 16, 64);
        pj += __shfl_xor(pj, 32, 64);
        if (q == 0) sm.s_cpart[0][colg] = pj;
        // reduce transpose partials over the 16 cols (L15 axis)
#pragma unroll
        for (int tr = 0; tr < 2; ++tr)
#pragma unroll
            for (int r = 0; r < 4; ++r) {
                float v = pt[tr][r];
                v += __shfl_xor(v, 1, 64);
                v += __shfl_xor(v, 2, 64);
                v += __shfl_xor(v, 4, 64);
                v += __shfl_xor(v, 8, 64);
                pt[tr][r] = v;
            }
        const int slotT = (w == 1) ? 1 : 2;   // rows 0-31 targets; w3 only uses slot1[32:63]
        if (L15 == 0) {
#pragma unroll
            for (int tr = 0; tr < 2; ++tr)
#pragma unroll
                for (int r = 0; r < 4; ++r)
                    sm.s_cpart[slotT][16 * tr + 4 * q + r] = pt[tr][r];
        }
    }
    __syncthreads();

    if (w == 0) {
        int j = lane;
        float c = sm.s_cpart[0][j] + sm.s_cpart[1][j] + (j < 32 ? sm.s_cpart[2][j] : 0.f);
        float aj = sm.s_a[j];
        bool valid = aj > 0.f;
        float cv = valid ? c : 3.4e38f;
        float mn = cv;
#pragma unroll
        for (int d = 1; d < 64; d <<= 1) mn = fminf(mn, __shfl_xor(mn, d, 64));
        float e = valid ? __expf(mn - c) * aj : 0.f;
        float s = e;
#pragma unroll
        for (int d = 1; d < 64; d <<= 1) s += __shfl_xor(s, d, 64);
        sm.s_u[j] = e * (sm.s_rsum / s);
    }
    __syncthreads();

    const int oct = t & 31, jb = t >> 5;
    float accd[8] = {0.f, 0.f, 0.f, 0.f, 0.f, 0.f, 0.f, 0.f};
#pragma unroll
    for (int jj = 0; jj < 8; ++jj) {
        int j = jb * 8 + jj;
        float u = sm.s_u[j];
        half8 xv;
        if (oct < 16) xv = *(const half8*)(Xhi + ((size_t)sm.s_cols[j] << 8) + oct * 8);
        else          xv = *(const half8*)&sm.sh[j][(oct - 16) * 8];
#pragma unroll
        for (int e = 0; e < 8; ++e) accd[e] = fmaf(u, (float)xv[e], accd[e]);
    }
#pragma unroll
    for (int e = 0; e < 8; ++e) accd[e] += __shfl_xor(accd[e], 32, 64);
    __syncthreads();   // sh reads above must drain before writing aliased s_red
    if (lane < 32) {
#pragma unroll
        for (int e = 0; e < 8; ++e) sm.s_red[w][9 * oct + e] = accd[e];
    }
    __syncthreads();
    const int idx = 9 * (t >> 3) + (t & 7);
    float o = sm.s_red[0][idx] + sm.s_red[1][idx] + sm.s_red[2][idx] + sm.s_red[3][idx];
    float res = fmaxf(o + bv, 0.f);
    size_t oi = (size_t)node * NHID + t;
    if (writeH) OutHi[oi] = (_Float16)res;
    else        OutF[oi] = res;
}

// ================================================================ D1: prep (xh, w1T, w2T) ∥ edge scatter
#define PREPB 512
__global__ __launch_bounds__(256) void k_prep_scatter(
    const float* __restrict__ x, _Float16* __restrict__ xh,
    const float* __restrict__ W1, _Float16* __restrict__ w1T,
    const float* __restrict__ W2, _Float16* __restrict__ w2T,
    const void* edges, int* rowcnt, int* nbr, int* deg, int E) {
    const int t = threadIdx.x;
    if ((int)blockIdx.x < PREPB) {
        const int gid = blockIdx.x * 256 + t, nthr = PREPB * 256;
        for (int i = gid; i < NNODE * 512 / 4; i += nthr) {
            float4 v = ((const float4*)x)[i];
            half4 h;
            h[0] = (_Float16)v.x; h[1] = (_Float16)v.y;
            h[2] = (_Float16)v.z; h[3] = (_Float16)v.w;
            *(half4*)&xh[4 * (size_t)i] = h;
        }
        for (int i = gid; i < 512 * NHID; i += nthr) {
            int k = i >> 8, n = i & 255;
            w1T[(size_t)n * 512 + k] = (_Float16)W1[i];
        }
        for (int i = gid; i < NHID * NHID; i += nthr) {
            int k = i >> 8, n = i & 255;
            w2T[(size_t)n * 256 + k] = (_Float16)W2[i];
        }
    } else {
        __shared__ int sflag;
        if (t < 64) {   // per-block dtype probe (L2-hot)
            const long long* e = (const long long*)edges;
            long long v = e[t];
            unsigned long long bad = __ballot(v < 0 || v >= (long long)NNODE);
            if (t == 0) sflag = (bad == 0) ? 1 : 0;
        }
        __syncthreads();
        const int fl = sflag;
        int i = ((int)blockIdx.x - PREPB) * 256 + t;
        if (i >= E + NNODE) return;
        int r, c;
        if (i < E) {
            if (fl) {
                const long long* e = (const long long*)edges;
                r = (int)e[i]; c = (int)e[E + i];
            } else {
                const int* e = (const int*)edges;
                r = e[i]; c = e[E + i];
            }
        } else { r = i - E; c = r; }   // self loop
        int pos = atomicAdd(&rowcnt[r], 1);
        if (pos < RCAP) nbr[r * RCAP + pos] = c;
        atomicAdd(&deg[c], 1);
    }
}

// ================================================================ D2: gemm1 (blocks 0..511) ∥ dedup
__global__ __launch_bounds__(256) void k_gemm1_dedup(
    const _Float16* __restrict__ xh, const _Float16* __restrict__ w1T,
    _Float16* __restrict__ X1,
    const int* __restrict__ nbr, const int* __restrict__ rowcnt,
    const int* __restrict__ deg,
    int* __restrict__ cols, float* __restrict__ wA, float* __restrict__ rsum) {
    __shared__ __align__(16) char smem[sizeof(SmemGemm)];
    if ((int)blockIdx.x < 512) {
        int g = blockIdx.x;
        gemm_body(smem, xh, w1T, X1, 512, (g >> 2) * 64, (g & 3) * 64);
    } else {
        dedup_body(smem, nbr, rowcnt, deg, cols, wA, rsum, (int)blockIdx.x - 512);
    }
}

// ================================================================ D3/D5: medoid layers
__global__ __launch_bounds__(256, 8) void k_medoid(
    const _Float16* __restrict__ X, const float* __restrict__ bias,
    float* __restrict__ OutF, _Float16* __restrict__ OutHi,
    const int* __restrict__ cols, const float* __restrict__ wts,
    const float* __restrict__ rsum, int writeH) {
    __shared__ __align__(16) SmemMedoid sm;
    const int node = blockIdx.x, t = threadIdx.x;
    float bv = bias[t];   // prefetch; latency hidden under cols/wts load + barrier
    if (t < 64) { sm.s_cols[t] = cols[node * KCAP + t]; sm.s_a[t] = wts[node * KCAP + t]; }
    if (t == 0) sm.s_rsum = rsum[node];
    __syncthreads();
    medoid_core(sm, X, bv, OutF, OutHi, node, writeH);
}

// ================================================================ D4: gemm layer 2
__global__ __launch_bounds__(256) void k_gemm2(
    const _Float16* __restrict__ Hh, const _Float16* __restrict__ w2T,
    _Float16* __restrict__ X2) {
    __shared__ __align__(16) char smem[sizeof(SmemGemm)];
    gemm_body(smem, Hh, w2T, X2, 256, blockIdx.x * 64, blockIdx.y * 64);
}

// ================================================================ launch
extern "C" void kernel_launch(void* const* d_in, const int* in_sizes, int n_in,
                              void* d_out, int out_size, void* d_ws, size_t ws_size,
                              hipStream_t stream) {
    const float* x  = (const float*)d_in[0];
    const void*  ei = d_in[1];
    const float* W1 = (const float*)d_in[2];
    const float* b1 = (const float*)d_in[3];
    const float* W2 = (const float*)d_in[4];
    const float* b2 = (const float*)d_in[5];
    float* out = (float*)d_out;
    const int E = in_sizes[1] / 2;

    char* p = (char*)d_ws;
    auto alloc = [&](size_t bytes) { char* q = p; p += (bytes + 255) & ~(size_t)255; return q; };
    int*      cnt    = (int*)alloc((size_t)2 * NNODE * 4);   // deg | rowcnt (single memset)
    int*      deg    = cnt;
    int*      rowcnt = cnt + NNODE;
    int*      colsA  = (int*)alloc((size_t)NNODE * KCAP * 4);
    float*    wAr    = (float*)alloc((size_t)NNODE * KCAP * 4);
    float*    rsum   = (float*)alloc((size_t)NNODE * 4);
    _Float16* xh     = (_Float16*)alloc((size_t)NNODE * 512 * 2);
    _Float16* w1T    = (_Float16*)alloc((size_t)512 * NHID * 2);
    _Float16* w2T    = (_Float16*)alloc((size_t)NHID * NHID * 2);
    _Float16* X1     = (_Float16*)alloc((size_t)NNODE * NHID * 2);   // also X2
    _Float16* Hh     = (_Float16*)alloc((size_t)NNODE * NHID * 2);
    int*      nbr    = (int*)alloc((size_t)NNODE * RCAP * 4);

    const int nscat = (E + NNODE + 255) / 256;

    hipMemsetAsync(cnt, 0, (size_t)2 * NNODE * 4, stream);
    k_prep_scatter<<<PREPB + nscat, 256, 0, stream>>>(x, xh, W1, w1T, W2, w2T,
                                                      ei, rowcnt, nbr, deg, E);
    k_gemm1_dedup<<<512 + NNODE / 2, 256, 0, stream>>>(xh, w1T, X1, nbr, rowcnt, deg,
                                                       colsA, wAr, rsum);
    k_medoid<<<NNODE, 256, 0, stream>>>(X1, b1, nullptr, Hh, colsA, wAr, rsum, 1);
    k_gemm2<<<dim3(NNODE / 64, NHID / 64), 256, 0, stream>>>(Hh, w2T, X1);
    k_medoid<<<NNODE, 256, 0, stream>>>(X1, b2, out, nullptr, colsA, wAr, rsum, 0);
}